// Round 1
// baseline (744.404 us; speedup 1.0000x reference)
//
#include <hip/hip_runtime.h>
#include <hip/hip_bf16.h>

// MessagePassing: out[dst[e], :] += x[src[e], :]
// x: [N=50000, D=64] fp32; edge_index: [2, E=800000] int (src row 0, dst row 1)
// Strategy (round 0): memset out to 0, then atomic scatter-add.
// 16 threads/edge, each thread handles one float4 (16 B) of the 256 B row.

#ifndef N_NODES_C
#define N_NODES_C 50000
#endif
#define D_FEAT_C 64

__global__ void mp_scatter_add(const float* __restrict__ x,
                               const int* __restrict__ src,
                               const int* __restrict__ dst,
                               float* __restrict__ out,
                               int n_edges) {
    int tid = blockIdx.x * blockDim.x + threadIdx.x;
    int edge = tid >> 4;        // 16 threads per edge
    int chunk = tid & 15;       // each covers 4 consecutive floats
    if (edge >= n_edges) return;

    int s = src[edge];
    int d = dst[edge];
    // bounds guard: fail loudly (wrong values) rather than segfault if the
    // index dtype assumption is wrong
    if ((unsigned)s >= (unsigned)N_NODES_C || (unsigned)d >= (unsigned)N_NODES_C)
        return;

    const float4 v =
        *reinterpret_cast<const float4*>(x + (size_t)s * D_FEAT_C + chunk * 4);
    float* o = out + (size_t)d * D_FEAT_C + chunk * 4;
    atomicAdd(o + 0, v.x);
    atomicAdd(o + 1, v.y);
    atomicAdd(o + 2, v.z);
    atomicAdd(o + 3, v.w);
}

extern "C" void kernel_launch(void* const* d_in, const int* in_sizes, int n_in,
                              void* d_out, int out_size, void* d_ws, size_t ws_size,
                              hipStream_t stream) {
    const float* x = (const float*)d_in[0];
    const int* edge_index = (const int*)d_in[1];
    float* out = (float*)d_out;

    const int n_edges = in_sizes[1] / 2;       // [2, E] flattened row-major
    const int* src = edge_index;               // edge_index[0]
    const int* dst = edge_index + n_edges;     // edge_index[1]

    // Output is poisoned with 0xAA before every timed call — zero it.
    hipMemsetAsync(d_out, 0, (size_t)out_size * sizeof(float), stream);

    const int threads_total = n_edges * 16;
    const int block = 256;
    const int grid = (threads_total + block - 1) / block;
    mp_scatter_add<<<grid, block, 0, stream>>>(x, src, dst, out, n_edges);
}

// Round 3
// 306.370 us; speedup vs baseline: 2.4298x; 2.4298x over previous
//
#include <hip/hip_runtime.h>
#include <hip/hip_bf16.h>

// MessagePassing: out[dst[e], :] += x[src[e], :]
// x: [N=50000, D=64] fp32; edge_index: [2, E=800000] int32 (src row, dst row)
// Round 1 strategy: build CSR per call (hist -> scan -> scatter), then a
// gather-sum kernel with 64 lanes/node. No fp32 atomics on the fat path.

#define N_NODES_C 50000
#define D_FEAT_C 64
#define SCAN_T 1024

__global__ void k_hist(const int* __restrict__ dst, int* __restrict__ deg, int E) {
    int i = blockIdx.x * blockDim.x + threadIdx.x;
    int stride = gridDim.x * blockDim.x;
    for (; i < E; i += stride) atomicAdd(&deg[dst[i]], 1);
}

__global__ void k_scan(const int* __restrict__ deg, int* __restrict__ offs,
                       int* __restrict__ cursor, int N) {
    int t = threadIdx.x;
    int chunk = (N + SCAN_T - 1) / SCAN_T;
    int lo = t * chunk;
    int hi = lo + chunk; if (hi > N) hi = N;
    if (lo > N) lo = N;

    int sum = 0;
    for (int i = lo; i < hi; ++i) sum += deg[i];

    __shared__ int s[SCAN_T];
    s[t] = sum;
    __syncthreads();
    // Hillis-Steele inclusive scan over 1024 partials
    for (int off = 1; off < SCAN_T; off <<= 1) {
        int v = (t >= off) ? s[t - off] : 0;
        __syncthreads();
        s[t] += v;
        __syncthreads();
    }
    int run = s[t] - sum;  // exclusive prefix for this thread's chunk
    for (int i = lo; i < hi; ++i) {
        offs[i] = run;
        cursor[i] = run;
        run += deg[i];
    }
    if (t == SCAN_T - 1) offs[N] = s[SCAN_T - 1];
}

__global__ void k_scatter(const int* __restrict__ src, const int* __restrict__ dst,
                          int* __restrict__ cursor, int* __restrict__ perm, int E) {
    int i = blockIdx.x * blockDim.x + threadIdx.x;
    int stride = gridDim.x * blockDim.x;
    for (; i < E; i += stride) {
        int p = atomicAdd(&cursor[dst[i]], 1);
        perm[p] = src[i];
    }
}

// 64 lanes per node: lane t accumulates feature t across the node's edges.
// blockDim = 256 -> 4 nodes per block.
__global__ void k_gather(const float* __restrict__ x, const int* __restrict__ perm,
                         const int* __restrict__ offs, float* __restrict__ out) {
    int node = blockIdx.x * (blockDim.x >> 6) + (threadIdx.x >> 6);
    int lane = threadIdx.x & 63;
    if (node >= N_NODES_C) return;

    int b = offs[node];
    int e = offs[node + 1];
    float acc0 = 0.f, acc1 = 0.f;
    int i = b;
    for (; i + 1 < e; i += 2) {
        int s0 = perm[i];
        int s1 = perm[i + 1];
        acc0 += x[(size_t)s0 * D_FEAT_C + lane];
        acc1 += x[(size_t)s1 * D_FEAT_C + lane];
    }
    if (i < e) acc0 += x[(size_t)perm[i] * D_FEAT_C + lane];
    out[(size_t)node * D_FEAT_C + lane] = acc0 + acc1;
}

extern "C" void kernel_launch(void* const* d_in, const int* in_sizes, int n_in,
                              void* d_out, int out_size, void* d_ws, size_t ws_size,
                              hipStream_t stream) {
    const float* x = (const float*)d_in[0];
    const int* edge_index = (const int*)d_in[1];
    float* out = (float*)d_out;

    const int E = in_sizes[1] / 2;            // [2, E] flattened row-major
    const int* src = edge_index;              // edge_index[0]
    const int* dst = edge_index + E;          // edge_index[1]

    // Workspace layout (ints): deg[N] | offs[N+1] | cursor[N+1] | perm[E]
    int* deg    = (int*)d_ws;
    int* offs   = deg + N_NODES_C;
    int* cursor = offs + N_NODES_C + 1;
    int* perm   = cursor + N_NODES_C + 1;

    hipMemsetAsync(deg, 0, (size_t)N_NODES_C * sizeof(int), stream);

    const int block = 256;
    const int gridE = 1024;  // grid-stride over E
    k_hist<<<gridE, block, 0, stream>>>(dst, deg, E);
    k_scan<<<1, SCAN_T, 0, stream>>>(deg, offs, cursor, N_NODES_C);
    k_scatter<<<gridE, block, 0, stream>>>(src, dst, cursor, perm, E);

    const int nodes_per_block = block / 64;   // 4
    const int gridN = (N_NODES_C + nodes_per_block - 1) / nodes_per_block;
    k_gather<<<gridN, block, 0, stream>>>(x, perm, offs, out);
}

// Round 5
// 206.140 us; speedup vs baseline: 3.6112x; 1.4862x over previous
//
#include <hip/hip_runtime.h>
#include <hip/hip_bf16.h>

// MessagePassing: out[dst[e], :] += x[src[e], :]
// x: [N=50000, D=64] fp32; edge_index: [2, E=800000] int32 (src row, dst row)
// Round 3: replace the single-block O(N)-serial scan (110 us!) with a
// 3-kernel parallel scan (part-sums -> scan block sums -> per-block offsets).
// CSR build + atomic-free gather otherwise unchanged.

#define N_NODES_C 50000
#define D_FEAT_C 64
#define SCAN_B 256
#define NB_SCAN ((N_NODES_C + SCAN_B - 1) / SCAN_B)   // 196

__global__ void k_hist(const int* __restrict__ dst, int* __restrict__ deg, int E) {
    int i = blockIdx.x * blockDim.x + threadIdx.x;
    int stride = gridDim.x * blockDim.x;
    for (; i < E; i += stride) atomicAdd(&deg[dst[i]], 1);
}

// Per-block reduction of 256 deg entries -> bsum[block]
__global__ void k_part(const int* __restrict__ deg, int* __restrict__ bsum, int N) {
    __shared__ int s[SCAN_B];
    int t = threadIdx.x;
    int i = blockIdx.x * SCAN_B + t;
    s[t] = (i < N) ? deg[i] : 0;
    __syncthreads();
    for (int off = SCAN_B / 2; off > 0; off >>= 1) {
        if (t < off) s[t] += s[t + off];
        __syncthreads();
    }
    if (t == 0) bsum[blockIdx.x] = s[0];
}

// Single small block: exclusive scan of nb (<=256) block sums; writes offs[N].
__global__ void k_scanb(const int* __restrict__ bsum, int* __restrict__ bpre,
                        int* __restrict__ offs, int nb, int N) {
    __shared__ int s[SCAN_B];
    int t = threadIdx.x;
    int v = (t < nb) ? bsum[t] : 0;
    s[t] = v;
    __syncthreads();
    for (int off = 1; off < SCAN_B; off <<= 1) {
        int u = (t >= off) ? s[t - off] : 0;
        __syncthreads();
        s[t] += u;
        __syncthreads();
    }
    if (t < nb) bpre[t] = s[t] - v;       // exclusive prefix of block sums
    if (t == SCAN_B - 1) offs[N] = s[SCAN_B - 1];  // grand total
}

// Intra-block exclusive scan + block prefix -> offs/cursor
__global__ void k_offs(const int* __restrict__ deg, const int* __restrict__ bpre,
                       int* __restrict__ offs, int* __restrict__ cursor, int N) {
    __shared__ int s[SCAN_B];
    int t = threadIdx.x;
    int i = blockIdx.x * SCAN_B + t;
    int v = (i < N) ? deg[i] : 0;
    s[t] = v;
    __syncthreads();
    for (int off = 1; off < SCAN_B; off <<= 1) {
        int u = (t >= off) ? s[t - off] : 0;
        __syncthreads();
        s[t] += u;
        __syncthreads();
    }
    if (i < N) {
        int o = bpre[blockIdx.x] + s[t] - v;
        offs[i] = o;
        cursor[i] = o;
    }
}

__global__ void k_scatter(const int* __restrict__ src, const int* __restrict__ dst,
                          int* __restrict__ cursor, int* __restrict__ perm, int E) {
    int i = blockIdx.x * blockDim.x + threadIdx.x;
    int stride = gridDim.x * blockDim.x;
    for (; i < E; i += stride) {
        int p = atomicAdd(&cursor[dst[i]], 1);
        perm[p] = src[i];
    }
}

// 64 lanes per node: lane t accumulates feature t across the node's edges.
__global__ void k_gather(const float* __restrict__ x, const int* __restrict__ perm,
                         const int* __restrict__ offs, float* __restrict__ out) {
    int node = blockIdx.x * (blockDim.x >> 6) + (threadIdx.x >> 6);
    int lane = threadIdx.x & 63;
    if (node >= N_NODES_C) return;

    int b = offs[node];
    int e = offs[node + 1];
    float acc0 = 0.f, acc1 = 0.f;
    int i = b;
    for (; i + 1 < e; i += 2) {
        int s0 = perm[i];
        int s1 = perm[i + 1];
        acc0 += x[(size_t)s0 * D_FEAT_C + lane];
        acc1 += x[(size_t)s1 * D_FEAT_C + lane];
    }
    if (i < e) acc0 += x[(size_t)perm[i] * D_FEAT_C + lane];
    out[(size_t)node * D_FEAT_C + lane] = acc0 + acc1;
}

extern "C" void kernel_launch(void* const* d_in, const int* in_sizes, int n_in,
                              void* d_out, int out_size, void* d_ws, size_t ws_size,
                              hipStream_t stream) {
    const float* x = (const float*)d_in[0];
    const int* edge_index = (const int*)d_in[1];
    float* out = (float*)d_out;

    const int E = in_sizes[1] / 2;            // [2, E] flattened row-major
    const int* src = edge_index;              // edge_index[0]
    const int* dst = edge_index + E;          // edge_index[1]

    // Workspace (ints): deg[N] | offs[N+1] | cursor[N] | bsum[NB] | bpre[NB] | perm[E]
    int* deg    = (int*)d_ws;
    int* offs   = deg + N_NODES_C;
    int* cursor = offs + N_NODES_C + 1;
    int* bsum   = cursor + N_NODES_C;
    int* bpre   = bsum + NB_SCAN;
    int* perm   = bpre + NB_SCAN;

    hipMemsetAsync(deg, 0, (size_t)N_NODES_C * sizeof(int), stream);

    const int block = 256;
    const int gridE = 1024;  // grid-stride over E
    k_hist<<<gridE, block, 0, stream>>>(dst, deg, E);
    k_part<<<NB_SCAN, SCAN_B, 0, stream>>>(deg, bsum, N_NODES_C);
    k_scanb<<<1, SCAN_B, 0, stream>>>(bsum, bpre, offs, NB_SCAN, N_NODES_C);
    k_offs<<<NB_SCAN, SCAN_B, 0, stream>>>(deg, bpre, offs, cursor, N_NODES_C);
    k_scatter<<<gridE, block, 0, stream>>>(src, dst, cursor, perm, E);

    const int nodes_per_block = block / 64;   // 4
    const int gridN = (N_NODES_C + nodes_per_block - 1) / nodes_per_block;
    k_gather<<<gridN, block, 0, stream>>>(x, perm, offs, out);
}

// Round 6
// 184.780 us; speedup vs baseline: 4.0286x; 1.1156x over previous
//
#include <hip/hip_runtime.h>
#include <hip/hip_bf16.h>

// MessagePassing: out[dst[e], :] += x[src[e], :]
// x: [N=50000, D=64] fp32; edge_index: [2, E=800000] int32 (src row, dst row)
// Round 5: scatter is write-amplification bound (52 MB HBM writes for 3.2 MB
// of perm payload). Store perm as uint16 (N < 65536), vectorize edge reads
// (int4), unroll gather x4. CSR structure otherwise unchanged.

#define N_NODES_C 50000
#define D_FEAT_C 64
#define SCAN_B 256
#define NB_SCAN ((N_NODES_C + SCAN_B - 1) / SCAN_B)   // 196

static_assert(N_NODES_C < 65536, "perm uses uint16 src indices");

__global__ void k_hist(const int* __restrict__ dst, int* __restrict__ deg, int E) {
    int i = blockIdx.x * blockDim.x + threadIdx.x;
    int stride = gridDim.x * blockDim.x;
    int n4 = E >> 2;
    const int4* d4 = (const int4*)dst;
    for (int j = i; j < n4; j += stride) {
        int4 v = d4[j];
        atomicAdd(&deg[v.x], 1);
        atomicAdd(&deg[v.y], 1);
        atomicAdd(&deg[v.z], 1);
        atomicAdd(&deg[v.w], 1);
    }
    for (int j = (n4 << 2) + i; j < E; j += stride) atomicAdd(&deg[dst[j]], 1);
}

// Per-block reduction of 256 deg entries -> bsum[block]
__global__ void k_part(const int* __restrict__ deg, int* __restrict__ bsum, int N) {
    __shared__ int s[SCAN_B];
    int t = threadIdx.x;
    int i = blockIdx.x * SCAN_B + t;
    s[t] = (i < N) ? deg[i] : 0;
    __syncthreads();
    for (int off = SCAN_B / 2; off > 0; off >>= 1) {
        if (t < off) s[t] += s[t + off];
        __syncthreads();
    }
    if (t == 0) bsum[blockIdx.x] = s[0];
}

// Single small block: exclusive scan of nb (<=256) block sums; writes offs[N].
__global__ void k_scanb(const int* __restrict__ bsum, int* __restrict__ bpre,
                        int* __restrict__ offs, int nb, int N) {
    __shared__ int s[SCAN_B];
    int t = threadIdx.x;
    int v = (t < nb) ? bsum[t] : 0;
    s[t] = v;
    __syncthreads();
    for (int off = 1; off < SCAN_B; off <<= 1) {
        int u = (t >= off) ? s[t - off] : 0;
        __syncthreads();
        s[t] += u;
        __syncthreads();
    }
    if (t < nb) bpre[t] = s[t] - v;       // exclusive prefix of block sums
    if (t == SCAN_B - 1) offs[N] = s[SCAN_B - 1];  // grand total
}

// Intra-block exclusive scan + block prefix -> offs/cursor
__global__ void k_offs(const int* __restrict__ deg, const int* __restrict__ bpre,
                       int* __restrict__ offs, int* __restrict__ cursor, int N) {
    __shared__ int s[SCAN_B];
    int t = threadIdx.x;
    int i = blockIdx.x * SCAN_B + t;
    int v = (i < N) ? deg[i] : 0;
    s[t] = v;
    __syncthreads();
    for (int off = 1; off < SCAN_B; off <<= 1) {
        int u = (t >= off) ? s[t - off] : 0;
        __syncthreads();
        s[t] += u;
        __syncthreads();
    }
    if (i < N) {
        int o = bpre[blockIdx.x] + s[t] - v;
        offs[i] = o;
        cursor[i] = o;
    }
}

__global__ void k_scatter(const int* __restrict__ src, const int* __restrict__ dst,
                          int* __restrict__ cursor, unsigned short* __restrict__ perm,
                          int E) {
    int i = blockIdx.x * blockDim.x + threadIdx.x;
    int stride = gridDim.x * blockDim.x;
    int n4 = E >> 2;
    const int4* s4 = (const int4*)src;
    const int4* d4 = (const int4*)dst;
    for (int j = i; j < n4; j += stride) {
        int4 s = s4[j];
        int4 d = d4[j];
        perm[atomicAdd(&cursor[d.x], 1)] = (unsigned short)s.x;
        perm[atomicAdd(&cursor[d.y], 1)] = (unsigned short)s.y;
        perm[atomicAdd(&cursor[d.z], 1)] = (unsigned short)s.z;
        perm[atomicAdd(&cursor[d.w], 1)] = (unsigned short)s.w;
    }
    for (int j = (n4 << 2) + i; j < E; j += stride) {
        perm[atomicAdd(&cursor[dst[j]], 1)] = (unsigned short)src[j];
    }
}

// 64 lanes per node: lane t accumulates feature t across the node's edges.
__global__ void k_gather(const float* __restrict__ x,
                         const unsigned short* __restrict__ perm,
                         const int* __restrict__ offs, float* __restrict__ out) {
    int node = blockIdx.x * (blockDim.x >> 6) + (threadIdx.x >> 6);
    int lane = threadIdx.x & 63;
    if (node >= N_NODES_C) return;

    int b = offs[node];
    int e = offs[node + 1];
    float a0 = 0.f, a1 = 0.f, a2 = 0.f, a3 = 0.f;
    int i = b;
    for (; i + 3 < e; i += 4) {
        int s0 = perm[i];
        int s1 = perm[i + 1];
        int s2 = perm[i + 2];
        int s3 = perm[i + 3];
        a0 += x[(size_t)s0 * D_FEAT_C + lane];
        a1 += x[(size_t)s1 * D_FEAT_C + lane];
        a2 += x[(size_t)s2 * D_FEAT_C + lane];
        a3 += x[(size_t)s3 * D_FEAT_C + lane];
    }
    for (; i < e; ++i) a0 += x[(size_t)perm[i] * D_FEAT_C + lane];
    out[(size_t)node * D_FEAT_C + lane] = (a0 + a1) + (a2 + a3);
}

extern "C" void kernel_launch(void* const* d_in, const int* in_sizes, int n_in,
                              void* d_out, int out_size, void* d_ws, size_t ws_size,
                              hipStream_t stream) {
    const float* x = (const float*)d_in[0];
    const int* edge_index = (const int*)d_in[1];
    float* out = (float*)d_out;

    const int E = in_sizes[1] / 2;            // [2, E] flattened row-major
    const int* src = edge_index;              // edge_index[0]
    const int* dst = edge_index + E;          // edge_index[1]

    // Workspace (ints): deg[N] | offs[N+1] | cursor[N] | bsum[NB] | bpre[NB] | perm16[E]
    int* deg    = (int*)d_ws;
    int* offs   = deg + N_NODES_C;
    int* cursor = offs + N_NODES_C + 1;
    int* bsum   = cursor + N_NODES_C;
    int* bpre   = bsum + NB_SCAN;
    unsigned short* perm = (unsigned short*)(bpre + NB_SCAN);

    hipMemsetAsync(deg, 0, (size_t)N_NODES_C * sizeof(int), stream);

    const int block = 256;
    const int gridE4 = ((E / 4) + block - 1) / block;  // 1 edge-quad per thread
    k_hist<<<gridE4, block, 0, stream>>>(dst, deg, E);
    k_part<<<NB_SCAN, SCAN_B, 0, stream>>>(deg, bsum, N_NODES_C);
    k_scanb<<<1, SCAN_B, 0, stream>>>(bsum, bpre, offs, NB_SCAN, N_NODES_C);
    k_offs<<<NB_SCAN, SCAN_B, 0, stream>>>(deg, bpre, offs, cursor, N_NODES_C);
    k_scatter<<<gridE4, block, 0, stream>>>(src, dst, cursor, perm, E);

    const int nodes_per_block = block / 64;   // 4
    const int gridN = (N_NODES_C + nodes_per_block - 1) / nodes_per_block;
    k_gather<<<gridN, block, 0, stream>>>(x, perm, offs, out);
}